// Round 8
// baseline (446.356 us; speedup 1.0000x reference)
//
#include <hip/hip_runtime.h>

// SSIM (32,3,512,512) fp32, separable 11x11 Gaussian, sqrt-free rational form.
// v8 = v7 + occupancy-cap workaround + fence instead of barrier.
//   v7 post-mortem: VALUBusy*dur constant (168 us) across v6/v7 -> VALU-issue
//   bound; OccupancyPercent stuck at 28.8% despite 24 waves/CU fitting ->
//   a per-CU cap on single-wave WORKGROUPS (~9) binds, not LDS/VGPR.
//   Fix: 4 independent waves per workgroup (each with its private ring in
//   shared LDS, 26 KB/WG -> 6 WG/CU = 24 waves/CU), NO inter-wave coupling:
//   __syncthreads replaced by __builtin_amdgcn_fence(ACQ_REL,"workgroup") --
//   compiler-ordering + lgkmcnt, no s_barrier. Fence BEFORE publish (WAR:
//   stop ds_write hoisting above prior step's reads) and AFTER publish (RAW:
//   stop ds_reads sinking above the write). DS ops per wave are FIFO in HW;
//   the fence only has to stop COMPILER reordering (v3 race lesson).
//   Also: branchless staging (clamped address + 0/1 mask mul, no exec dance),
//   drop 3 wasted drain steps (T_TOTAL=74).
// Carried: waves_per_eu(min,max) min caps regs, max stops spill-chasing
// (v2/v5/v6); readfirstlane is int(int) -> bit-cast floats (v4).

#define IMG_H 512
#define IMG_W 512
#define N_IMGS 96                    // 32 batch * 3 channels
#define WAVE_W 64                    // output cols per wave
#define STRIPE 64                    // output rows per wave
#define HALO 5
#define KW 11
#define IN_COLS (WAVE_W + 2*HALO)    // 74
#define NWAVES 4                     // independent waves per workgroup
#define N_STRIPES (N_IMGS * 8 * 8)   // 6144 wave-stripes
#define N_BLOCKS (N_STRIPES / NWAVES)          // 1536 workgroups
#define T_TOTAL 74                   // rows staged per stripe (64 + 10 halo)
#define NBINS 256
#define TOTAL_PIX (32.0f * 3.0f * 512.0f * 512.0f)

#define LDS_FENCE() __builtin_amdgcn_fence(__ATOMIC_ACQ_REL, "workgroup")

__global__ __launch_bounds__(64 * NWAVES)
__attribute__((amdgpu_waves_per_eu(2, 6)))
void ssim_main(
    const float* __restrict__ img1, const float* __restrict__ img2,
    const float* __restrict__ window, float* __restrict__ bins)
{
    __shared__ float2 ring[NWAVES][KW][IN_COLS];   // 26048 B, per-wave private

    const int tid  = threadIdx.x;
    const int wav  = tid >> 6;            // 0..3, wave-uniform
    const int lane = tid & 63;

    // 1D gaussian, wave-uniform (SGPRs): g[k] = w[5][k] / sqrt(w[5][5]).
    float g[KW];
    {
        const float inv = rsqrtf(window[5*KW + 5]);
        #pragma unroll
        for (int k = 0; k < KW; ++k)
            g[k] = __int_as_float(
                __builtin_amdgcn_readfirstlane(
                    __float_as_int(window[5*KW + k] * inv)));
    }

    // Global stripe id for this wave.
    const int S   = blockIdx.x * NWAVES + wav;
    const int img = S >> 6;               // 8x8 stripes per image
    const int rem = S & 63;
    const int ty  = rem >> 3;             // 0..7 row stripe
    const int tx  = rem & 7;              // 0..7 col stripe
    const int r0  = ty * STRIPE;
    const int x0  = tx * WAVE_W;

    const float* __restrict__ p1 = img1 + (size_t)img * (IMG_H * IMG_W);
    const float* __restrict__ p2 = img2 + (size_t)img * (IMG_H * IMG_W);

    float2 (* __restrict__ wring)[IN_COLS] = ring[wav];

    // Branchless staging: clamped column indices + 0/1 masks (loads are
    // always in-bounds; OOB lanes multiply by 0).
    const int  gx1 = x0 - HALO + lane;
    const int  gx2 = gx1 + WAVE_W;
    const int  cx1 = min(max(gx1, 0), IMG_W - 1);
    const int  cx2 = min(max(gx2, 0), IMG_W - 1);
    const float cm1 = ((unsigned)gx1 < IMG_W) ? 1.f : 0.f;
    const float cm2 = ((unsigned)gx2 < IMG_W) ? 1.f : 0.f;
    const bool tail = lane < (IN_COLS - WAVE_W);    // lanes 0..9 store 2nd elt

    // h-value register ring (5 signals x 11 slots) -- stays in VGPRs.
    float r_h1[KW], r_h2[KW], r_h11[KW], r_h22[KW], r_h12[KW];
    #pragma unroll
    for (int i = 0; i < KW; ++i) {
        r_h1[i] = 0.f; r_h2[i] = 0.f; r_h11[i] = 0.f; r_h22[i] = 0.f; r_h12[i] = 0.f;
    }

    const float C1 = 1e-4f;   // (0.01*1.0)^2
    const float C2 = 9e-4f;   // (0.03*1.0)^2
    float sum = 0.f;

    // Prologue: load input row t=0 (gy = r0-5), branchless.
    float sa, sb, sa2, sb2;
    {
        const int gy  = r0 - HALO;
        const int gyc = min(max(gy, 0), IMG_H - 1);
        const float rm = ((unsigned)gy < IMG_H) ? 1.f : 0.f;
        const float* r1 = p1 + gyc * IMG_W;
        const float* r2 = p2 + gyc * IMG_W;
        const float m1 = rm * cm1, m2 = rm * cm2;
        sa  = r1[cx1] * m1;  sb  = r2[cx1] * m1;
        sa2 = r1[cx2] * m2;  sb2 = r2[cx2] * m2;
    }

    #pragma unroll 1
    for (int tb = 0; tb < T_TOTAL; tb += KW) {
        #pragma unroll
        for (int u = 0; u < KW; ++u) {       // t % 11 == u, static ring slots
            const int t = tb + u;
            if (t >= T_TOTAL) break;         // uniform; trims 3 drain steps

            // 1) Publish row t into ring slot u (fences stop compiler
            //    reordering across the cross-lane LDS dependency).
            LDS_FENCE();                     // WAR vs prior step's reads
            wring[u][lane] = make_float2(sa, sb);
            if (tail) wring[u][lane + WAVE_W] = make_float2(sa2, sb2);
            LDS_FENCE();                     // RAW for this step's reads

            // 2) Issue global loads for row t+1 (branchless, waited next step).
            {
                const int gy  = r0 - HALO + t + 1;
                const int gyc = min(max(gy, 0), IMG_H - 1);
                const float rm = ((unsigned)gy < IMG_H) ? 1.f : 0.f;
                const float* r1 = p1 + gyc * IMG_W;
                const float* r2 = p2 + gyc * IMG_W;
                const float m1 = rm * cm1, m2 = rm * cm2;
                sa  = r1[cx1] * m1;  sb  = r2[cx1] * m1;
                sa2 = r1[cx2] * m2;  sb2 = r2[cx2] * m2;
            }

            // 3) Horizontal 11-tap conv at col x0+lane from ring slot u.
            float h1 = 0.f, h2 = 0.f, h11 = 0.f, h22 = 0.f, h12 = 0.f;
            #pragma unroll
            for (int k = 0; k < KW; ++k) {
                const float2 v = wring[u][lane + k];
                const float t1 = g[k] * v.x;
                const float t2 = g[k] * v.y;
                h1  += t1;
                h2  += t2;
                h11 += t1 * v.x;
                h22 += t2 * v.y;
                h12 += t1 * v.y;
            }
            r_h1[u] = h1; r_h2[u] = h2; r_h11[u] = h11; r_h22[u] = h22; r_h12[u] = h12;

            // 4) Vertical gather + SSIM for output row r0 + t - 10
            //    (uniform branch).
            if (t >= 2*HALO) {
                float mu1 = 0.f, mu2 = 0.f, e11 = 0.f, e22 = 0.f, e12 = 0.f;
                #pragma unroll
                for (int m = 0; m < KW; ++m) {
                    const int slot = (u + 1 + m) % KW;  // compile-time index
                    mu1 += g[m] * r_h1[slot];
                    mu2 += g[m] * r_h2[slot];
                    e11 += g[m] * r_h11[slot];
                    e22 += g[m] * r_h22[slot];
                    e12 += g[m] * r_h12[slot];
                }
                const float mu1s = mu1 * mu1, mu2s = mu2 * mu2, mu12 = mu1 * mu2;
                const float s1  = fmaxf(e11 - mu1s, 0.f);
                const float s2  = fmaxf(e22 - mu2s, 0.f);
                const float s12 = e12 - mu12;
                const float num = (2.f * mu12 + C1) * (2.f * s12 + C2);
                const float den = (mu1s + mu2s + C1) * (s1 + s2 + C2);
                sum += num * __builtin_amdgcn_rcpf(den);
            }
        }
    }

    // Per-wave reduction -> one atomicAdd per wave, fanned over 256 bins.
    #pragma unroll
    for (int off = 32; off > 0; off >>= 1)
        sum += __shfl_down(sum, off, 64);
    if (lane == 0)
        atomicAdd(&bins[S & (NBINS - 1)], sum);
}

__global__ __launch_bounds__(64) void ssim_final(
    const float* __restrict__ bins, float* __restrict__ out)
{
    const int tid = threadIdx.x;
    float s = 0.f;
    #pragma unroll
    for (int i = 0; i < NBINS / 64; ++i) s += bins[tid + i * 64];
    #pragma unroll
    for (int off = 32; off > 0; off >>= 1)
        s += __shfl_down(s, off, 64);
    if (tid == 0) out[0] = s * (1.0f / TOTAL_PIX);
}

extern "C" void kernel_launch(void* const* d_in, const int* in_sizes, int n_in,
                              void* d_out, int out_size, void* d_ws, size_t ws_size,
                              hipStream_t stream) {
    const float* img1   = (const float*)d_in[0];
    const float* img2   = (const float*)d_in[1];
    const float* window = (const float*)d_in[2];
    float* bins = (float*)d_ws;
    float* out  = (float*)d_out;

    hipMemsetAsync(bins, 0, NBINS * sizeof(float), stream);
    ssim_main<<<N_BLOCKS, 64 * NWAVES, 0, stream>>>(img1, img2, window, bins);
    ssim_final<<<1, 64, 0, stream>>>(bins, out);
}